// Round 13
// baseline (241.391 us; speedup 1.0000x reference)
//
#include <hip/hip_runtime.h>
#include <hip/hip_bf16.h>

typedef __hip_bfloat16 bf16;
typedef __attribute__((ext_vector_type(8))) __bf16 bf16x8;
typedef __attribute__((ext_vector_type(4))) float floatx4;

#define NB 2
#define NL 2048
#define NC 1024
#define NH 16
#define ND 64

__device__ __forceinline__ void async_copy16(void* lds, const void* g) {
  __builtin_amdgcn_global_load_lds(
      (__attribute__((address_space(1))) void*)(const_cast<void*>(g)),
      (__attribute__((address_space(3))) void*)(lds), 16, 0, 0);
}

__device__ __forceinline__ floatx4 mfma16(bf16x8 a, bf16x8 b, floatx4 c) {
  return __builtin_amdgcn_mfma_f32_16x16x32_bf16(a, b, c, 0, 0, 0);
}

// ---------------- GroupNorm partial stats: 512 blocks = (bg, L/8 slice) -----
__global__ __launch_bounds__(256) void gn_part_kernel(
    const float* __restrict__ x, float2* __restrict__ part) {
  int bg = blockIdx.x >> 3, sl = blockIdx.x & 7;
  int b = bg >> 5, g = bg & 31;
  const float* base = x + (size_t)b * NL * NC + (size_t)(sl * 256) * NC + g * 32;
  float s = 0.f, ss = 0.f;
  for (int vi = threadIdx.x; vi < 2048; vi += 256) {
    int l = vi >> 3, j = (vi & 7) * 4;
    float4 u = *(const float4*)(base + (size_t)l * NC + j);
    s += u.x + u.y + u.z + u.w;
    ss += u.x * u.x + u.y * u.y + u.z * u.z + u.w * u.w;
  }
  for (int off = 32; off; off >>= 1) {
    s += __shfl_down(s, off);
    ss += __shfl_down(ss, off);
  }
  __shared__ float rs[4], rss[4];
  int wave = threadIdx.x >> 6, lane = threadIdx.x & 63;
  if (lane == 0) { rs[wave] = s; rss[wave] = ss; }
  __syncthreads();
  if (threadIdx.x == 0) {
    part[blockIdx.x] = make_float2(rs[0] + rs[1] + rs[2] + rs[3],
                                   rss[0] + rss[1] + rss[2] + rss[3]);
  }
}

// ---------------- GroupNorm apply (folds partial reduction) -----------------
__global__ __launch_bounds__(256) void gn_apply_kernel(
    const float* __restrict__ x, const float2* __restrict__ part,
    const float* __restrict__ scale, const float* __restrict__ bias,
    bf16* __restrict__ xn) {
  size_t idx = (size_t)blockIdx.x * 256 + threadIdx.x;
  size_t e = idx * 8;
  int c = (int)(e & (NC - 1));
  int b = (int)(e >> 21);
  int bg = b * 32 + (c >> 5);
  float s = 0.f, ss = 0.f;
#pragma unroll
  for (int i = 0; i < 8; ++i) {
    float2 p = part[bg * 8 + i];
    s += p.x; ss += p.y;
  }
  float mean = s * (1.f / 65536.f);
  float var = ss * (1.f / 65536.f) - mean * mean;
  float rstd = rsqrtf(var + 1e-6f);
  float4 x0 = *(const float4*)(x + e);
  float4 x1 = *(const float4*)(x + e + 4);
  float4 s0 = *(const float4*)(scale + c);
  float4 s1 = *(const float4*)(scale + c + 4);
  float4 b0 = *(const float4*)(bias + c);
  float4 b1 = *(const float4*)(bias + c + 4);
  float xv[8] = {x0.x, x0.y, x0.z, x0.w, x1.x, x1.y, x1.z, x1.w};
  float sv[8] = {s0.x, s0.y, s0.z, s0.w, s1.x, s1.y, s1.z, s1.w};
  float bv[8] = {b0.x, b0.y, b0.z, b0.w, b1.x, b1.y, b1.z, b1.w};
  bf16 o[8];
#pragma unroll
  for (int k = 0; k < 8; ++k)
    o[k] = __float2bfloat16((xv[k] - mean) * rstd * sv[k] + bv[k]);
  *(uint4*)(xn + e) = *(const uint4*)o;
}

// ---------------- transpose + convert: fp32 [R,C] -> bf16 [C,R] -------------
__global__ void transpose_f32_bf16(const float* __restrict__ in,
                                   bf16* __restrict__ out, int R, int C) {
  __shared__ float t[32][33];
  int c0 = blockIdx.x * 32, r0 = blockIdx.y * 32;
#pragma unroll
  for (int j = 0; j < 4; ++j)
    t[threadIdx.y + j * 8][threadIdx.x] =
        in[(size_t)(r0 + threadIdx.y + j * 8) * C + c0 + threadIdx.x];
  __syncthreads();
#pragma unroll
  for (int j = 0; j < 4; ++j)
    out[(size_t)(c0 + threadIdx.y + j * 8) * R + r0 + threadIdx.x] =
        __float2bfloat16(t[threadIdx.x][threadIdx.y + j * 8]);
}

// ---------------- GEMM: C[M,N] = A[M,K] * Bt[N,K]^T + bias ------------------
// Tile 128 x NT (NT in {128,64}); NT=64 doubles blocks/CU for small N.
// MODE 0: scatter into Q*0.125 [b,h,l,d], K[b,h,l,d], Vt[b,h,d,l]  (bf16)
// MODE 1: out_f32 = (xres + C) / sqrt(2)
template <int MODE, int NT>
__global__ __launch_bounds__(256) void gemm_kernel(
    const bf16* __restrict__ A, const bf16* __restrict__ Bt,
    const float* __restrict__ biasv, const float* __restrict__ xres,
    bf16* __restrict__ Qo, bf16* __restrict__ Ko, bf16* __restrict__ Vto,
    float* __restrict__ out, int M, int N, int K) {
  constexpr int NFR = NT / 32;   // n-frags per wave
  __shared__ bf16 As[128 * 32];
  __shared__ bf16 Bs[NT * 32];
  int tid = threadIdx.x, wave = tid >> 6, lane = tid & 63;
  int col = lane & 15, quad = lane >> 4;
  int mB = blockIdx.y * 128, nB = blockIdx.x * NT;
  int wm = (wave >> 1) * 64, wn = (wave & 1) * (NT / 2);
  floatx4 acc[4][NFR];
#pragma unroll
  for (int i = 0; i < 4; ++i)
#pragma unroll
    for (int j = 0; j < NFR; ++j) acc[i][j] = (floatx4){0.f, 0.f, 0.f, 0.f};

  int rowOff = wave * 32 + (lane >> 2);
  int rowOffB = (NT == 128) ? rowOff : (wave * 16 + (lane >> 2));
  int kOff = (lane & 3) * 8;

  for (int k0 = 0; k0 < K; k0 += 32) {
    __syncthreads();
    const bf16* ga = A + (size_t)(mB + rowOff) * K + k0 + kOff;
    async_copy16(&As[(wave * 32) * 32], ga);
    async_copy16(&As[(wave * 32 + 16) * 32], ga + (size_t)16 * K);
    const bf16* gb = Bt + (size_t)(nB + rowOffB) * K + k0 + kOff;
    if (NT == 128) {
      async_copy16(&Bs[(wave * 32) * 32], gb);
      async_copy16(&Bs[(wave * 32 + 16) * 32], gb + (size_t)16 * K);
    } else {
      async_copy16(&Bs[(wave * 16) * 32], gb);
    }
    __syncthreads();
    bf16x8 af[4], bfr[NFR];
#pragma unroll
    for (int mi = 0; mi < 4; ++mi)
      af[mi] = *(const bf16x8*)&As[(wm + mi * 16 + col) * 32 + quad * 8];
#pragma unroll
    for (int ni = 0; ni < NFR; ++ni)
      bfr[ni] = *(const bf16x8*)&Bs[(wn + ni * 16 + col) * 32 + quad * 8];
#pragma unroll
    for (int mi = 0; mi < 4; ++mi)
#pragma unroll
      for (int ni = 0; ni < NFR; ++ni)
        acc[mi][ni] = mfma16(af[mi], bfr[ni], acc[mi][ni]);
  }

#pragma unroll
  for (int mi = 0; mi < 4; ++mi)
#pragma unroll
    for (int ni = 0; ni < NFR; ++ni)
#pragma unroll
      for (int r = 0; r < 4; ++r) {
        int row = mB + wm + mi * 16 + quad * 4 + r;
        int ncol = nB + wn + ni * 16 + col;
        float v = acc[mi][ni][r] + biasv[ncol];
        if (MODE == 0) {
          int b = row >> 11, f = row & 2047;
          int h = ncol / 192, rr = ncol - h * 192;
          size_t bhl = ((size_t)(b * NH + h) * NL + f);
          if (rr < 64)
            Qo[bhl * 64 + rr] = __float2bfloat16(v * 0.125f);  // 1/sqrt(hd)
          else if (rr < 128)
            Ko[bhl * 64 + rr - 64] = __float2bfloat16(v);
          else
            Vto[((size_t)(b * NH + h) * 64 + (rr - 128)) * NL + f] = __float2bfloat16(v);
        } else {
          size_t o = (size_t)row * N + ncol;
          out[o] = (xres[o] + v) * 0.70710678118654752f;
        }
      }
}

// ---------------- Flash attention v9: t-split + conflict-free P' ------------
// v8 t-split (10 b128 LDS reads per 16 MFMA) but P' rows at stride 64 with
// octet XOR swizzle: write b64 at chunk ct^(m&7) -> 8 bank classes x 2 lanes
// = 2-way (free, m136); read b128 likewise. v8's stride-32 layout only had 4
// classes -> 4-way conflicts (the r12 regression). LDS 48KB -> 3 blocks/CU.
__global__ __launch_bounds__(256, 3) void attn_kernel(
    const bf16* __restrict__ Q, const bf16* __restrict__ Kb,
    const bf16* __restrict__ Vt, bf16* __restrict__ hout) {
  int qt = blockIdx.x, bh = blockIdx.y;
  int b = bh >> 4, h = bh & 15;
  int tid = threadIdx.x, wave = tid >> 6, lane = tid & 63;
  int m = lane & 15, quad = lane >> 4;
  int tg = wave >> 1, th = wave & 1;   // q-group, t-half

  __shared__ bf16 Kd[2][4096];   // [buf][64 t-rows x 64], XOR-swizzled chunks
  __shared__ bf16 Vd[2][4096];   // [buf][64 d-rows x 64], XOR-swizzled
  __shared__ bf16 Pp[4][2048];   // per-wave P' [32 m-rows][stride 64], swizzled

  bf16* Psw = Pp[wave];

  const bf16* Kg = Kb + (size_t)bh * NL * 64;   // K row t: stride 64
  const bf16* Vg = Vt + (size_t)bh * 64 * NL;   // V row d: stride NL

  // ---- Q fragments: one-time direct global gather ----
  bf16x8 bq[2][2];
  {
    const bf16* Qg = Q + ((size_t)bh * NL + qt * 64 + tg * 32) * 64;
#pragma unroll
    for (int nf = 0; nf < 2; ++nf)
#pragma unroll
      for (int c = 0; c < 2; ++c)
        bq[nf][c] = *(const bf16x8*)&Qg[(size_t)(nf * 16 + m) * 64 + c * 32 + quad * 8];
  }

  float lrow[2] = {0.f, 0.f};
  floatx4 o[2][4];
#pragma unroll
  for (int nf = 0; nf < 2; ++nf)
#pragma unroll
    for (int di = 0; di < 4; ++di) o[nf][di] = (floatx4){0.f, 0.f, 0.f, 0.f};

  int srow = lane >> 3, schunk = lane & 7;   // staging decomposition

  auto stage = [&](int bufi, int t0) {
#pragma unroll
    for (int i = 0; i < 2; ++i) {
      int r0 = wave * 16 + i * 8;          // this 1KB chunk = rows r0..r0+7
      int r = r0 + srow;
      int cg = schunk ^ (r & 7);           // permuted source chunk
      async_copy16(&Kd[bufi][r0 * 64], Kg + (size_t)(t0 + r) * 64 + cg * 8);
      async_copy16(&Vd[bufi][r0 * 64], Vg + (size_t)r * NL + t0 + cg * 8);
    }
  };

  stage(0, 0);
  __syncthreads();

  int buf = 0;
  for (int t0 = 0; t0 < NL; t0 += 64) {
    if (t0 + 64 < NL) stage(buf ^ 1, t0 + 64);  // async prefetch next tile

    const bf16* Kbase = Kd[buf];
    const bf16* Vbase = Vd[buf];

    // ---- S' = K * Q^T on this wave's t-half (rows th*32 + ti*16 + ...) ----
    floatx4 s[2][2];
#pragma unroll
    for (int nf = 0; nf < 2; ++nf)
#pragma unroll
      for (int ti = 0; ti < 2; ++ti) s[nf][ti] = (floatx4){0.f, 0.f, 0.f, 0.f};
#pragma unroll
    for (int ti = 0; ti < 2; ++ti)
#pragma unroll
      for (int c = 0; c < 2; ++c) {
        bf16x8 ak = *(const bf16x8*)
            &Kbase[(th * 32 + ti * 16 + m) * 64 + ((c * 4 + quad) ^ (m & 7)) * 8];
        s[0][ti] = mfma16(ak, bq[0][c], s[0][ti]);
        s[1][ti] = mfma16(ak, bq[1][c], s[1][ti]);
      }

    // ---- softmax accumulate (no max; GN-bounded) + P' -> LDS (swizzled) ----
#pragma unroll
    for (int nf = 0; nf < 2; ++nf) {
      float ls = 0.f;
#pragma unroll
      for (int ti = 0; ti < 2; ++ti)
#pragma unroll
        for (int r = 0; r < 4; ++r) {
          float p = __expf(s[nf][ti][r]);
          s[nf][ti][r] = p;
          ls += p;
        }
      ls += __shfl_xor(ls, 16);
      ls += __shfl_xor(ls, 32);
      lrow[nf] += ls;   // partial over this t-half; th-pair summed at end
#pragma unroll
      for (int ti = 0; ti < 2; ++ti) {
        bf16 pk[4];
#pragma unroll
        for (int r = 0; r < 4; ++r) pk[r] = __float2bfloat16(s[nf][ti][r]);
        int ct = ti * 2 + (quad >> 1);   // logical t-chunk 0..3 within 32
        *(uint2*)&Psw[(nf * 16 + m) * 64 + ((ct ^ (m & 7)) * 8) + (quad & 1) * 4] =
            *(const uint2*)pk;
      }
    }

    // ---- O^T += V^T(this t-half) * P'  (wave-private LDS, no barrier) ----
    bf16x8 bp[2];
#pragma unroll
    for (int nf = 0; nf < 2; ++nf)
      bp[nf] = *(const bf16x8*)&Psw[(nf * 16 + m) * 64 + ((quad ^ (m & 7)) * 8)];
#pragma unroll
    for (int di = 0; di < 4; ++di) {
      bf16x8 av = *(const bf16x8*)
          &Vbase[(di * 16 + m) * 64 + ((th * 4 + quad) ^ (m & 7)) * 8];
      o[0][di] = mfma16(av, bp[0], o[0][di]);
      o[1][di] = mfma16(av, bp[1], o[1][di]);
    }

    __syncthreads();  // releases buf for overwrite; drains prefetch vmcnt
    buf ^= 1;
  }

  // ---- th-pair reduction via dead K/V buffers (lane-contiguous, no conflict)
  float* So = (float*)Kd;   // 4096 floats: [tg][32 slots][64 lanes]
  float* Sl = (float*)Vd;   // [tg][2 nf][64 lanes]
  if (th == 1) {
#pragma unroll
    for (int nf = 0; nf < 2; ++nf) {
      Sl[tg * 128 + nf * 64 + lane] = lrow[nf];
#pragma unroll
      for (int di = 0; di < 4; ++di)
#pragma unroll
        for (int r = 0; r < 4; ++r)
          So[tg * 2048 + (nf * 16 + di * 4 + r) * 64 + lane] = o[nf][di][r];
    }
  }
  __syncthreads();
  if (th == 0) {
#pragma unroll
    for (int nf = 0; nf < 2; ++nf) {
      lrow[nf] += Sl[tg * 128 + nf * 64 + lane];
#pragma unroll
      for (int di = 0; di < 4; ++di)
#pragma unroll
        for (int r = 0; r < 4; ++r)
          o[nf][di][r] += So[tg * 2048 + (nf * 16 + di * 4 + r) * 64 + lane];
    }
#pragma unroll
    for (int nf = 0; nf < 2; ++nf) {
      float rl = 1.f / lrow[nf];
      int l = qt * 64 + tg * 32 + nf * 16 + m;
      bf16* hp = hout + (size_t)(b * NL + l) * NC + h * 64;
#pragma unroll
      for (int di = 0; di < 4; ++di) {
        bf16 pk[4];
#pragma unroll
        for (int r = 0; r < 4; ++r) pk[r] = __float2bfloat16(o[nf][di][r] * rl);
        *(uint2*)&hp[di * 16 + quad * 4] = *(const uint2*)pk;
      }
    }
  }
}

extern "C" void kernel_launch(void* const* d_in, const int* in_sizes, int n_in,
                              void* d_out, int out_size, void* d_ws, size_t ws_size,
                              hipStream_t stream) {
  const float* x = (const float*)d_in[0];
  const float* gn_scale = (const float*)d_in[1];
  const float* gn_bias = (const float*)d_in[2];
  const float* qkv_w = (const float*)d_in[3];
  const float* qkv_b = (const float*)d_in[4];
  const float* proj_w = (const float*)d_in[5];
  const float* proj_b = (const float*)d_in[6];
  float* out = (float*)d_out;

  bf16* xn = (bf16*)d_out;  // aliases d_out first half; dead before GEMM1

  char* ws = (char*)d_ws;
  float2* part = (float2*)ws;               // 512 float2 = 4096 B exactly
  bf16* Qb = (bf16*)(ws + 4096);
  bf16* Kbuf = Qb + 4194304;
  bf16* Vt = Kbuf + 4194304;
  bf16* hat = Vt + 4194304;
  bf16* wqkvT = hat;   // aliased: dead before attn writes hat
  bf16* projT = Qb;    // aliased: written after attn, Q dead

  gn_part_kernel<<<512, 256, 0, stream>>>(x, part);
  gn_apply_kernel<<<2048, 256, 0, stream>>>(x, part, gn_scale, gn_bias, xn);
  transpose_f32_bf16<<<dim3(96, 32), dim3(32, 8), 0, stream>>>(qkv_w, wqkvT, 1024, 3072);
  gemm_kernel<0, 128><<<dim3(24, 32), 256, 0, stream>>>(
      xn, wqkvT, qkv_b, nullptr, Qb, Kbuf, Vt, nullptr, 4096, 3072, 1024);
  attn_kernel<<<dim3(32, 32), 256, 0, stream>>>(Qb, Kbuf, Vt, hat);
  transpose_f32_bf16<<<dim3(32, 32), dim3(32, 8), 0, stream>>>(proj_w, projT, 1024, 1024);
  gemm_kernel<1, 64><<<dim3(16, 32), 256, 0, stream>>>(
      hat, projT, proj_b, x, nullptr, nullptr, nullptr, out, 4096, 1024, 1024);
}

// Round 14
// 218.150 us; speedup vs baseline: 1.1065x; 1.1065x over previous
//
#include <hip/hip_runtime.h>
#include <hip/hip_bf16.h>

typedef __hip_bfloat16 bf16;
typedef __attribute__((ext_vector_type(8))) __bf16 bf16x8;
typedef __attribute__((ext_vector_type(4))) float floatx4;

#define NB 2
#define NL 2048
#define NC 1024
#define NH 16
#define ND 64

__device__ __forceinline__ void async_copy16(void* lds, const void* g) {
  __builtin_amdgcn_global_load_lds(
      (__attribute__((address_space(1))) void*)(const_cast<void*>(g)),
      (__attribute__((address_space(3))) void*)(lds), 16, 0, 0);
}

__device__ __forceinline__ floatx4 mfma16(bf16x8 a, bf16x8 b, floatx4 c) {
  return __builtin_amdgcn_mfma_f32_16x16x32_bf16(a, b, c, 0, 0, 0);
}

// ---------------- GroupNorm partial stats: 512 blocks = (bg, L/8 slice) -----
__global__ __launch_bounds__(256) void gn_part_kernel(
    const float* __restrict__ x, float2* __restrict__ part) {
  int bg = blockIdx.x >> 3, sl = blockIdx.x & 7;
  int b = bg >> 5, g = bg & 31;
  const float* base = x + (size_t)b * NL * NC + (size_t)(sl * 256) * NC + g * 32;
  float s = 0.f, ss = 0.f;
  for (int vi = threadIdx.x; vi < 2048; vi += 256) {
    int l = vi >> 3, j = (vi & 7) * 4;
    float4 u = *(const float4*)(base + (size_t)l * NC + j);
    s += u.x + u.y + u.z + u.w;
    ss += u.x * u.x + u.y * u.y + u.z * u.z + u.w * u.w;
  }
  for (int off = 32; off; off >>= 1) {
    s += __shfl_down(s, off);
    ss += __shfl_down(ss, off);
  }
  __shared__ float rs[4], rss[4];
  int wave = threadIdx.x >> 6, lane = threadIdx.x & 63;
  if (lane == 0) { rs[wave] = s; rss[wave] = ss; }
  __syncthreads();
  if (threadIdx.x == 0) {
    part[blockIdx.x] = make_float2(rs[0] + rs[1] + rs[2] + rs[3],
                                   rss[0] + rss[1] + rss[2] + rss[3]);
  }
}

// ---------------- GroupNorm apply (folds partial reduction) -----------------
__global__ __launch_bounds__(256) void gn_apply_kernel(
    const float* __restrict__ x, const float2* __restrict__ part,
    const float* __restrict__ scale, const float* __restrict__ bias,
    bf16* __restrict__ xn) {
  size_t idx = (size_t)blockIdx.x * 256 + threadIdx.x;
  size_t e = idx * 8;
  int c = (int)(e & (NC - 1));
  int b = (int)(e >> 21);
  int bg = b * 32 + (c >> 5);
  float s = 0.f, ss = 0.f;
#pragma unroll
  for (int i = 0; i < 8; ++i) {
    float2 p = part[bg * 8 + i];
    s += p.x; ss += p.y;
  }
  float mean = s * (1.f / 65536.f);
  float var = ss * (1.f / 65536.f) - mean * mean;
  float rstd = rsqrtf(var + 1e-6f);
  float4 x0 = *(const float4*)(x + e);
  float4 x1 = *(const float4*)(x + e + 4);
  float4 s0 = *(const float4*)(scale + c);
  float4 s1 = *(const float4*)(scale + c + 4);
  float4 b0 = *(const float4*)(bias + c);
  float4 b1 = *(const float4*)(bias + c + 4);
  float xv[8] = {x0.x, x0.y, x0.z, x0.w, x1.x, x1.y, x1.z, x1.w};
  float sv[8] = {s0.x, s0.y, s0.z, s0.w, s1.x, s1.y, s1.z, s1.w};
  float bv[8] = {b0.x, b0.y, b0.z, b0.w, b1.x, b1.y, b1.z, b1.w};
  bf16 o[8];
#pragma unroll
  for (int k = 0; k < 8; ++k)
    o[k] = __float2bfloat16((xv[k] - mean) * rstd * sv[k] + bv[k]);
  *(uint4*)(xn + e) = *(const uint4*)o;
}

// ---------------- transpose + convert: fp32 [R,C] -> bf16 [C,R] -------------
__global__ void transpose_f32_bf16(const float* __restrict__ in,
                                   bf16* __restrict__ out, int R, int C) {
  __shared__ float t[32][33];
  int c0 = blockIdx.x * 32, r0 = blockIdx.y * 32;
#pragma unroll
  for (int j = 0; j < 4; ++j)
    t[threadIdx.y + j * 8][threadIdx.x] =
        in[(size_t)(r0 + threadIdx.y + j * 8) * C + c0 + threadIdx.x];
  __syncthreads();
#pragma unroll
  for (int j = 0; j < 4; ++j)
    out[(size_t)(c0 + threadIdx.y + j * 8) * R + r0 + threadIdx.x] =
        __float2bfloat16(t[threadIdx.x][threadIdx.y + j * 8]);
}

// ---------------- GEMM: C[M,N] = A[M,K] * Bt[N,K]^T + bias ------------------
// Tile 128 x NT (NT in {128,64}); NT=64 doubles blocks/CU for small N.
// MODE 0: scatter into Q*0.125 [b,h,l,d], K[b,h,l,d], Vt[b,h,d,l]  (bf16)
// MODE 1: out_f32 = (xres + C) / sqrt(2)
template <int MODE, int NT>
__global__ __launch_bounds__(256) void gemm_kernel(
    const bf16* __restrict__ A, const bf16* __restrict__ Bt,
    const float* __restrict__ biasv, const float* __restrict__ xres,
    bf16* __restrict__ Qo, bf16* __restrict__ Ko, bf16* __restrict__ Vto,
    float* __restrict__ out, int M, int N, int K) {
  constexpr int NFR = NT / 32;   // n-frags per wave
  __shared__ bf16 As[128 * 32];
  __shared__ bf16 Bs[NT * 32];
  int tid = threadIdx.x, wave = tid >> 6, lane = tid & 63;
  int col = lane & 15, quad = lane >> 4;
  int mB = blockIdx.y * 128, nB = blockIdx.x * NT;
  int wm = (wave >> 1) * 64, wn = (wave & 1) * (NT / 2);
  floatx4 acc[4][NFR];
#pragma unroll
  for (int i = 0; i < 4; ++i)
#pragma unroll
    for (int j = 0; j < NFR; ++j) acc[i][j] = (floatx4){0.f, 0.f, 0.f, 0.f};

  int rowOff = wave * 32 + (lane >> 2);
  int rowOffB = (NT == 128) ? rowOff : (wave * 16 + (lane >> 2));
  int kOff = (lane & 3) * 8;

  for (int k0 = 0; k0 < K; k0 += 32) {
    __syncthreads();
    const bf16* ga = A + (size_t)(mB + rowOff) * K + k0 + kOff;
    async_copy16(&As[(wave * 32) * 32], ga);
    async_copy16(&As[(wave * 32 + 16) * 32], ga + (size_t)16 * K);
    const bf16* gb = Bt + (size_t)(nB + rowOffB) * K + k0 + kOff;
    if (NT == 128) {
      async_copy16(&Bs[(wave * 32) * 32], gb);
      async_copy16(&Bs[(wave * 32 + 16) * 32], gb + (size_t)16 * K);
    } else {
      async_copy16(&Bs[(wave * 16) * 32], gb);
    }
    __syncthreads();
    bf16x8 af[4], bfr[NFR];
#pragma unroll
    for (int mi = 0; mi < 4; ++mi)
      af[mi] = *(const bf16x8*)&As[(wm + mi * 16 + col) * 32 + quad * 8];
#pragma unroll
    for (int ni = 0; ni < NFR; ++ni)
      bfr[ni] = *(const bf16x8*)&Bs[(wn + ni * 16 + col) * 32 + quad * 8];
#pragma unroll
    for (int mi = 0; mi < 4; ++mi)
#pragma unroll
      for (int ni = 0; ni < NFR; ++ni)
        acc[mi][ni] = mfma16(af[mi], bfr[ni], acc[mi][ni]);
  }

#pragma unroll
  for (int mi = 0; mi < 4; ++mi)
#pragma unroll
    for (int ni = 0; ni < NFR; ++ni)
#pragma unroll
      for (int r = 0; r < 4; ++r) {
        int row = mB + wm + mi * 16 + quad * 4 + r;
        int ncol = nB + wn + ni * 16 + col;
        float v = acc[mi][ni][r] + biasv[ncol];
        if (MODE == 0) {
          int b = row >> 11, f = row & 2047;
          int h = ncol / 192, rr = ncol - h * 192;
          size_t bhl = ((size_t)(b * NH + h) * NL + f);
          if (rr < 64)
            Qo[bhl * 64 + rr] = __float2bfloat16(v * 0.125f);  // 1/sqrt(hd)
          else if (rr < 128)
            Ko[bhl * 64 + rr - 64] = __float2bfloat16(v);
          else
            Vto[((size_t)(b * NH + h) * 64 + (rr - 128)) * NL + f] = __float2bfloat16(v);
        } else {
          size_t o = (size_t)row * N + ncol;
          out[o] = (xres[o] + v) * 0.70710678118654752f;
        }
      }
}

// ---------------- Flash attention v10: 8-wave blocks, 256 Q rows/block ------
// Phase-lock model (r13): epoch cost is ~fixed per barrier-iteration, so
// amortize it: one staged K/V tile (16 KB) feeds 8 waves x 32 Q-rows = 256
// rows/block (4x v7's rows per staged byte; 2x v6). Grid (8,32)=256 blocks,
// 1/CU. Per-wave compute = v6 structure with v9's conflict-free stride-64
// XOR-swizzled P'. Q-frags one-time direct global. Double-buffered
// global_load_lds staging (2 copies/wave), one barrier/iter.
__global__ __launch_bounds__(512, 2) void attn_kernel(
    const bf16* __restrict__ Q, const bf16* __restrict__ Kb,
    const bf16* __restrict__ Vt, bf16* __restrict__ hout) {
  int qt = blockIdx.x, bh = blockIdx.y;
  int b = bh >> 4, h = bh & 15;
  int tid = threadIdx.x, wave = tid >> 6, lane = tid & 63;
  int m = lane & 15, quad = lane >> 4;

  __shared__ bf16 Kd[2][4096];   // [buf][64 t-rows x 64], XOR-swizzled chunks
  __shared__ bf16 Vd[2][4096];   // [buf][64 d-rows x 64], XOR-swizzled
  __shared__ bf16 Pp[8][2048];   // per-wave P' [32 m-rows][stride 64], swizzled

  bf16* Psw = Pp[wave];

  const bf16* Kg = Kb + (size_t)bh * NL * 64;   // K row t: stride 64
  const bf16* Vg = Vt + (size_t)bh * 64 * NL;   // V row d: stride NL

  // ---- Q fragments: one-time direct global gather (rows qt*256+wave*32+...)
  bf16x8 bq[2][2];
  {
    const bf16* Qg = Q + ((size_t)bh * NL + qt * 256 + wave * 32) * 64;
#pragma unroll
    for (int nf = 0; nf < 2; ++nf)
#pragma unroll
      for (int c = 0; c < 2; ++c)
        bq[nf][c] = *(const bf16x8*)&Qg[(size_t)(nf * 16 + m) * 64 + c * 32 + quad * 8];
  }

  float lrow[2] = {0.f, 0.f};
  floatx4 o[2][4];
#pragma unroll
  for (int nf = 0; nf < 2; ++nf)
#pragma unroll
    for (int di = 0; di < 4; ++di) o[nf][di] = (floatx4){0.f, 0.f, 0.f, 0.f};

  int srow = lane >> 3, schunk = lane & 7;   // staging decomposition

  // 8 waves x (1 K-copy + 1 V-copy) of 1 KB each = 16 KB tile
  auto stage = [&](int bufi, int t0) {
    int r0 = wave * 8;                   // this wave's 8-row chunk
    int r = r0 + srow;
    int cg = schunk ^ (r & 7);           // permuted source chunk
    async_copy16(&Kd[bufi][r0 * 64], Kg + (size_t)(t0 + r) * 64 + cg * 8);
    async_copy16(&Vd[bufi][r0 * 64], Vg + (size_t)r * NL + t0 + cg * 8);
  };

  stage(0, 0);
  __syncthreads();

  int buf = 0;
  for (int t0 = 0; t0 < NL; t0 += 64) {
    if (t0 + 64 < NL) stage(buf ^ 1, t0 + 64);  // async prefetch next tile

    const bf16* Kbase = Kd[buf];
    const bf16* Vbase = Vd[buf];

    // ---- S' = K * Q^T : rows t, cols m (Q pre-scaled by 0.125) ----
    floatx4 s[2][4];
#pragma unroll
    for (int nf = 0; nf < 2; ++nf)
#pragma unroll
      for (int ti = 0; ti < 4; ++ti) s[nf][ti] = (floatx4){0.f, 0.f, 0.f, 0.f};
#pragma unroll
    for (int ti = 0; ti < 4; ++ti)
#pragma unroll
      for (int c = 0; c < 2; ++c) {
        bf16x8 ak = *(const bf16x8*)
            &Kbase[(ti * 16 + m) * 64 + ((c * 4 + quad) ^ (m & 7)) * 8];
        s[0][ti] = mfma16(ak, bq[0][c], s[0][ti]);
        s[1][ti] = mfma16(ak, bq[1][c], s[1][ti]);
      }

    // ---- softmax accumulate (no max; GN-bounded) + P' -> LDS (swizzled) ----
#pragma unroll
    for (int nf = 0; nf < 2; ++nf) {
      float ls = 0.f;
#pragma unroll
      for (int ti = 0; ti < 4; ++ti)
#pragma unroll
        for (int r = 0; r < 4; ++r) {
          float p = __expf(s[nf][ti][r]);
          s[nf][ti][r] = p;
          ls += p;
        }
      ls += __shfl_xor(ls, 16);
      ls += __shfl_xor(ls, 32);
      lrow[nf] += ls;
#pragma unroll
      for (int ti = 0; ti < 4; ++ti) {
        bf16 pk[4];
#pragma unroll
        for (int r = 0; r < 4; ++r) pk[r] = __float2bfloat16(s[nf][ti][r]);
        int ct = ti * 2 + (quad >> 1);   // logical t-chunk 0..7
        *(uint2*)&Psw[(nf * 16 + m) * 64 + ((ct ^ (m & 7)) * 8) + (quad & 1) * 4] =
            *(const uint2*)pk;
      }
    }

    // ---- O^T += V^T * P'  (wave-private LDS, lgkmcnt-ordered, no barrier) --
#pragma unroll
    for (int c = 0; c < 2; ++c) {
      bf16x8 bp[2];
#pragma unroll
      for (int nf = 0; nf < 2; ++nf)
        bp[nf] = *(const bf16x8*)
            &Psw[(nf * 16 + m) * 64 + (((c * 4 + quad) ^ (m & 7)) * 8)];
#pragma unroll
      for (int di = 0; di < 4; ++di) {
        bf16x8 av = *(const bf16x8*)
            &Vbase[(di * 16 + m) * 64 + ((c * 4 + quad) ^ (m & 7)) * 8];
        o[0][di] = mfma16(av, bp[0], o[0][di]);
        o[1][di] = mfma16(av, bp[1], o[1][di]);
      }
    }

    __syncthreads();  // releases buf for overwrite; drains prefetch vmcnt
    buf ^= 1;
  }

  // ---- epilogue: O^T[d][m] / l -> hat[b, l, h*64+d] ----
#pragma unroll
  for (int nf = 0; nf < 2; ++nf) {
    float rl = 1.f / lrow[nf];
    int l = qt * 256 + wave * 32 + nf * 16 + m;
    bf16* hp = hout + (size_t)(b * NL + l) * NC + h * 64;
#pragma unroll
    for (int di = 0; di < 4; ++di) {
      bf16 pk[4];
#pragma unroll
      for (int r = 0; r < 4; ++r) pk[r] = __float2bfloat16(o[nf][di][r] * rl);
      *(uint2*)&hp[di * 16 + quad * 4] = *(const uint2*)pk;
    }
  }
}

extern "C" void kernel_launch(void* const* d_in, const int* in_sizes, int n_in,
                              void* d_out, int out_size, void* d_ws, size_t ws_size,
                              hipStream_t stream) {
  const float* x = (const float*)d_in[0];
  const float* gn_scale = (const float*)d_in[1];
  const float* gn_bias = (const float*)d_in[2];
  const float* qkv_w = (const float*)d_in[3];
  const float* qkv_b = (const float*)d_in[4];
  const float* proj_w = (const float*)d_in[5];
  const float* proj_b = (const float*)d_in[6];
  float* out = (float*)d_out;

  bf16* xn = (bf16*)d_out;  // aliases d_out first half; dead before GEMM1

  char* ws = (char*)d_ws;
  float2* part = (float2*)ws;               // 512 float2 = 4096 B exactly
  bf16* Qb = (bf16*)(ws + 4096);
  bf16* Kbuf = Qb + 4194304;
  bf16* Vt = Kbuf + 4194304;
  bf16* hat = Vt + 4194304;
  bf16* wqkvT = hat;   // aliased: dead before attn writes hat
  bf16* projT = Qb;    // aliased: written after attn, Q dead

  gn_part_kernel<<<512, 256, 0, stream>>>(x, part);
  gn_apply_kernel<<<2048, 256, 0, stream>>>(x, part, gn_scale, gn_bias, xn);
  transpose_f32_bf16<<<dim3(96, 32), dim3(32, 8), 0, stream>>>(qkv_w, wqkvT, 1024, 3072);
  gemm_kernel<0, 128><<<dim3(24, 32), 256, 0, stream>>>(
      xn, wqkvT, qkv_b, nullptr, Qb, Kbuf, Vt, nullptr, 4096, 3072, 1024);
  attn_kernel<<<dim3(8, 32), 512, 0, stream>>>(Qb, Kbuf, Vt, hat);
  transpose_f32_bf16<<<dim3(32, 32), dim3(32, 8), 0, stream>>>(proj_w, projT, 1024, 1024);
  gemm_kernel<1, 64><<<dim3(16, 32), 256, 0, stream>>>(
      hat, projT, proj_b, x, nullptr, nullptr, nullptr, out, 4096, 1024, 1024);
}